// Round 6
// baseline (2877.947 us; speedup 1.0000x reference)
//
#include <hip/hip_runtime.h>
#include <math.h>

constexpr int kB  = 256;
constexpr int kT  = 512;
constexpr int kNS = 64;
constexpr int kH  = 128;

// WhhT rows 0..255 cached in LDS (fp32), padded to 132 floats/row: lane bank
// = 4*(u+k4) % 32 -> all 32 banks hit uniformly per b128 read.
constexpr int kWRowsLds = 256;
constexpr int kWPad     = 132;

__device__ __forceinline__ float sigmoidf_(float v) { return 1.0f / (1.0f + __expf(-v)); }
// fast tanh via exp (saturates correctly at +/-1 for large |v|)
__device__ __forceinline__ float tanhf_(float v) {
    return 1.0f - 2.0f / (1.0f + __expf(2.0f * v));
}
__device__ __forceinline__ float dot4(float4 a, float4 b) {
    return a.x*b.x + a.y*b.y + a.z*b.z + a.w*b.w;
}

// ---- DPP cross-lane reduce (4 VALU DPP + 2 DS ops) ------------------------
template <int CTRL>
__device__ __forceinline__ float dppf(float x) {
    return __int_as_float(__builtin_amdgcn_mov_dpp(__float_as_int(x), CTRL, 0xf, 0xf, true));
}
__device__ __forceinline__ float red_max64(float x) {
    x = fmaxf(x, dppf<0xB1>(x));
    x = fmaxf(x, dppf<0x4E>(x));
    x = fmaxf(x, dppf<0x124>(x));
    x = fmaxf(x, dppf<0x128>(x));
    x = fmaxf(x, __shfl_xor(x, 16, 64));
    x = fmaxf(x, __shfl_xor(x, 32, 64));
    return x;
}
__device__ __forceinline__ float red_sum64(float x) {
    x += dppf<0xB1>(x);
    x += dppf<0x4E>(x);
    x += dppf<0x124>(x);
    x += dppf<0x128>(x);
    x += __shfl_xor(x, 16, 64);
    x += __shfl_xor(x, 32, 64);
    return x;
}

// One-time: transpose Whh[128][384] -> WhhT[384][128] in d_ws.
extern "C" __global__ void __launch_bounds__(256)
whh_transpose(const float* __restrict__ Whh, float* __restrict__ WhhT) {
    const int o = blockIdx.x * 256 + threadIdx.x;   // 0..49151
    const int j = o >> 7, k = o & 127;
    WhhT[o] = Whh[k * 384 + j];
}

// One block (512 threads) per batch row. R15: TWO barriers/step.
//   P1: redundant tail(t-1) on ALL waves (gate/err/s2 as wave-uniform regs,
//       per-wave sh_s copy) -> K(t) dual-row -> gh(t) (w1-4 LDS, w5-6 L2)
//   P2: einsum (all waves) + GRU (threads 0-127, fast tanh) + w7 prefetch
extern "C" __global__ void __launch_bounds__(512, 2)
disc_kernel(const float* __restrict__ x,   const float* __restrict__ y,
            const float* __restrict__ U,   const float* __restrict__ S,
            const float* __restrict__ A,   const float* __restrict__ Wih,
            const float* __restrict__ bih, const float* __restrict__ bhh,
            const float* __restrict__ Wd,  const float* __restrict__ bd,
            const float* __restrict__ WhhT,
            float* __restrict__ out_o,  float* __restrict__ out_p)
{
    const int b    = blockIdx.x;
    const int tid  = threadIdx.x;
    const int lane = tid & 63;
    const int wid  = tid >> 6;
    const int hb   = tid & 1;

    __shared__ __align__(16) float sh_K[768];
    __shared__ __align__(16) float sh_part[512];
    __shared__ __align__(16) float sh_part2[512];
    __shared__ __align__(16) float sh_gh[384];
    __shared__ __align__(16) float sh_h[kH];          // single buffer (GRU RMW)
    __shared__ __align__(16) float sh_sW[8][kNS];     // per-wave s copy (no races)
    __shared__ __align__(16) float sh_Wih[4 * 384];
    __shared__ __align__(16) float sh_bih[384];
    __shared__ __align__(16) float sh_bhh[384];
    __shared__ float sh_Wd[384];
    __shared__ float sh_bd[4];
    __shared__ float sh_encA[8];
    __shared__ float sh_encB[8];
    __shared__ __align__(16) float sh_xt[2][4];       // parity double buffer
    __shared__ float sh_yt[2];
    // 256 x 132 fp32 = 135168 B; block total ~154 KB (<=160 KB, 1 blk/CU)
    __shared__ __align__(16) float sh_W[kWRowsLds * kWPad];

    // ---- Persistent register caches (R4 layout; at the register wall) -----
    const float4* S4 = reinterpret_cast<const float4*>(S);
    const float4* U4 = reinterpret_cast<const float4*>(U);

    float4 Sa[16]; float4 Ua; float Ca;       // full K-row = tid
    float4 Sb[8];  float Ub0, Ub1; float Cb;  // half of K-row 512+(tid>>1)
    {
        float ss = 0.f;
#pragma unroll
        for (int j = 0; j < 16; ++j) { Sa[j] = S4[tid * 16 + j]; ss += dot4(Sa[j], Sa[j]); }
        Ua = U4[tid];
        Ca = -0.5f * (dot4(Ua, Ua) + ss);
    }
    const int pbrow = 512 + (tid >> 1);
    {
        float ss = 0.f;
#pragma unroll
        for (int j = 0; j < 8; ++j) { Sb[j] = S4[pbrow * 16 + hb * 8 + j]; ss += dot4(Sb[j], Sb[j]); }
        Ub0 = U[pbrow * 4 + hb * 2 + 0];
        Ub1 = U[pbrow * 4 + hb * 2 + 1];
        Cb = -0.5f * (Ub0*Ub0 + Ub1*Ub1 + ss);
    }
    // Einsum A caches — wave-uniform chunk mapping (conflict-free K broadcast)
    float A1[64];
#pragma unroll
    for (int dd = 0; dd < 64; ++dd)
        A1[dd] = A[((wid >> 2) * 256 + (wid & 3) * 64 + dd) * 64 + lane];
    float A2[32];
#pragma unroll
    for (int dd = 0; dd < 32; ++dd)
        A2[dd] = A[(512 + (wid >> 1) * 64 + (wid & 1) * 32 + dd) * 64 + lane];

    // Replicated (wave-uniform) recurrence scalars — identical in all waves
    float g0 = 0.3333f, g1 = 0.3333f, g2 = 0.3334f;
    float err = 1.0f, s2 = 0.f;

    // ---- LDS preload -----------------------------------------------------
    for (int i = tid; i < 1536; i += 512) sh_Wih[i] = Wih[i];
    for (int i = tid; i < 384; i += 512) {
        sh_bih[i] = bih[i];
        sh_bhh[i] = bhh[i];
        sh_gh[i]  = bhh[i];                   // gh(t=0) with h=0
        sh_Wd[i]  = (i < 381) ? Wd[i] : 0.f;
    }
    for (int i4 = tid; i4 < kWRowsLds * 32; i4 += 512) {
        const int r = i4 >> 5, c4 = i4 & 31;
        reinterpret_cast<float4*>(sh_W + r * kWPad)[c4] =
            reinterpret_cast<const float4*>(WhhT)[i4];
    }
    sh_sW[wid][lane] = 0.f;
    if (tid < 3) sh_bd[tid] = bd[tid];
    if (tid < kH) sh_h[tid] = 0.f;
    if (tid == 0) {
        float4 xv = reinterpret_cast<const float4*>(x)[(size_t)b * kT];
        reinterpret_cast<float4*>(sh_xt[0])[0] = xv;
        sh_yt[0] = y[(size_t)b * kT];
    }
    __syncthreads();

    // Redundant tail for step (tp): reads sh_h, sh_part(+2), sh_Wd, sh_yt.
    // Updates g0..g2 / err / s2 (wave-uniform regs), writes this wave's sh_s
    // copy; wave 0 stores the two outputs.
    auto tail_step = [&](int tp) {
        const float hA = sh_h[lane];
        const float hB = sh_h[64 + lane];
        const float theta = sigmoidf_(sh_h[127]);
        float l0 = hA * sh_Wd[lane*3+0] + hB * sh_Wd[(64+lane)*3+0];
        float l1 = hA * sh_Wd[lane*3+1] + hB * sh_Wd[(64+lane)*3+1];
        float l2 = hA * sh_Wd[lane*3+2] + hB * sh_Wd[(64+lane)*3+2];
        l0 = red_sum64(l0) + sh_bd[0];
        l1 = red_sum64(l1) + sh_bd[1];
        l2 = red_sum64(l2) + sh_bd[2];
        const float mx = fmaxf(l0, fmaxf(l1, l2));
        const float x0 = __expf(l0 - mx), x1 = __expf(l1 - mx), x2e = __expf(l2 - mx);
        const float inv = theta / (x0 + x1 + x2e);
        const float omt = 1.f - theta;
        g0 = x0*inv + g0*omt;
        g1 = x1*inv + g1*omt;
        g2 = x2e*inv + g2*omt;
        const float ns0 = (sh_part[lane]       + sh_part[64 + lane])
                        + (sh_part[128 + lane] + sh_part[192 + lane]);
        const float ns1 = (sh_part[256 + lane] + sh_part[320 + lane])
                        + (sh_part[384 + lane] + sh_part[448 + lane]);
        const float ns2 = ((sh_part2[lane]       + sh_part2[64 + lane])
                        +  (sh_part2[128 + lane] + sh_part2[192 + lane]))
                        + ((sh_part2[256 + lane] + sh_part2[320 + lane])
                        +  (sh_part2[384 + lane] + sh_part2[448 + lane]));
        const float sn = g0*ns0 + g1*ns1 + g2*ns2;
        sh_sW[wid][lane] = sn;
        if (wid == 0) {
            if (lane == 0)
                out_p[(size_t)b * kT + tp] = g0*(1.f-g0) + g1*(1.f-g1) + g2*(1.f-g2);
            if (lane == 63)
                out_o[(size_t)b * kT + tp] = sn;
        }
        err = __shfl(sn, 63, 64) - sh_yt[tp & 1];
        s2  = red_sum64(sn * sn);
    };

    for (int t = 0; t < kT; ++t) {
        const int cur = t & 1;

        // ===== P1: tail(t-1) [all waves] -> K(t) -> gh(t) ==================
        if (t > 0) tail_step(t - 1);
        {
            const float4 xt4 = reinterpret_cast<const float4*>(sh_xt[cur])[0];
            const float xx2 = dot4(xt4, xt4);
            const float scal = -0.5f * (xx2 + s2);
            const float4* s4 = reinterpret_cast<const float4*>(sh_sW[wid]);
            float da0 = 0.f, da1 = 0.f, dblo = 0.f, dbhi = 0.f;
#pragma unroll
            for (int j = 0; j < 8; ++j) {
                const float4 sv0 = s4[j];
                const float4 sv1 = s4[8 + j];
                da0  += dot4(sv0, Sa[j]);
                da1  += dot4(sv1, Sa[8 + j]);
                dblo += dot4(sv0, Sb[j]);
                dbhi += dot4(sv1, Sb[j]);
            }
            const float db = hb ? dbhi : dblo;
            const float kk_a = __expf(scal + Ca + dot4(xt4, Ua) + da0 + da1);
            const float xbp  = hb ? (xt4.z*Ub0 + xt4.w*Ub1) : (xt4.x*Ub0 + xt4.y*Ub1);
            const float ph   = db + Cb + xbp;
            const float po   = dppf<0xB1>(ph);
            const float kk_b = __expf(scal + ph + po);
            sh_K[tid] = kk_a;
            if (hb == 0) sh_K[512 + (tid >> 1)] = kk_b;
            const float mA = red_max64(kk_a);
            const float mB = red_max64(kk_b);
            if (lane == 0) { sh_encA[wid] = mA; sh_encB[wid] = mB; }
        }
        if (wid >= 1 && wid <= 4) {                        // rows 0..255 (LDS)
            const int u = tid - 64;
            const float4* W4 = reinterpret_cast<const float4*>(sh_W + u * kWPad);
            const float4* h4 = reinterpret_cast<const float4*>(sh_h);
            float ga = sh_bhh[u], gb = 0.f;
#pragma unroll 8
            for (int k4 = 0; k4 < 32; k4 += 2) {
                ga += dot4(h4[k4],     W4[k4]);
                gb += dot4(h4[k4 + 1], W4[k4 + 1]);
            }
            sh_gh[u] = ga + gb;
        } else if (wid == 5 || wid == 6) {                 // rows 256..383 (L2)
            const int u = 256 + (tid - 320);
            const float4* W4 = reinterpret_cast<const float4*>(WhhT) + u * 32;
            const float4* h4 = reinterpret_cast<const float4*>(sh_h);
            float ga = sh_bhh[u], gb = 0.f;
#pragma unroll 8
            for (int k4 = 0; k4 < 32; k4 += 2) {
                ga += dot4(h4[k4],     W4[k4]);
                gb += dot4(h4[k4 + 1], W4[k4 + 1]);
            }
            sh_gh[u] = ga + gb;
        }
        __syncthreads();                                   // (A)

        // ===== P2: einsum (all waves) + GRU (0-127) + w7 prefetch ==========
        {
            const float4* K4 = reinterpret_cast<const float4*>(sh_K + wid * 64);
            float acc = 0.f;
#pragma unroll
            for (int j = 0; j < 16; ++j) {
                const float4 kv = K4[j];
                acc += kv.x*A1[4*j] + kv.y*A1[4*j+1] + kv.z*A1[4*j+2] + kv.w*A1[4*j+3];
            }
            sh_part[tid] = acc;
            const float4* K4b = reinterpret_cast<const float4*>(
                                    sh_K + 512 + (wid >> 1) * 64 + (wid & 1) * 32);
            float accb = 0.f;
#pragma unroll
            for (int j = 0; j < 8; ++j) {
                const float4 kv = K4b[j];
                accb += kv.x*A2[4*j] + kv.y*A2[4*j+1] + kv.z*A2[4*j+2] + kv.w*A2[4*j+3];
            }
            sh_part2[tid] = accb;
        }
        if (tid < 128) {
            const float e0 = fmaxf(fmaxf(sh_encA[0], sh_encA[1]), fmaxf(sh_encA[2], sh_encA[3]));
            const float e1 = fmaxf(fmaxf(sh_encA[4], sh_encA[5]), fmaxf(sh_encA[6], sh_encA[7]));
            const float e2 = fmaxf(fmaxf(fmaxf(sh_encB[0], sh_encB[1]), fmaxf(sh_encB[2], sh_encB[3])),
                                   fmaxf(fmaxf(sh_encB[4], sh_encB[5]), fmaxf(sh_encB[6], sh_encB[7])));
            const float er = err;                          // wave-uniform register
            const int j = tid;
            const float gir = sh_bih[j]       + e0*sh_Wih[j]        + e1*sh_Wih[384 + j]
                                              + e2*sh_Wih[768 + j]  + er*sh_Wih[1152 + j];
            const float giz = sh_bih[128 + j] + e0*sh_Wih[128 + j]  + e1*sh_Wih[512 + j]
                                              + e2*sh_Wih[896 + j]  + er*sh_Wih[1280 + j];
            const float gin = sh_bih[256 + j] + e0*sh_Wih[256 + j]  + e1*sh_Wih[640 + j]
                                              + e2*sh_Wih[1024 + j] + er*sh_Wih[1408 + j];
            const float r  = sigmoidf_(gir + sh_gh[j]);
            const float z  = sigmoidf_(giz + sh_gh[128 + j]);
            const float nn = tanhf_(gin + r * sh_gh[256 + j]);
            sh_h[j] = (1.f - z) * nn + z * sh_h[j];        // RMW by owner thread
        }
        if (wid == 7 && lane == 0 && (t + 1) < kT) {
            float4 xv = reinterpret_cast<const float4*>(x)[(size_t)b * kT + t + 1];
            reinterpret_cast<float4*>(sh_xt[(t + 1) & 1])[0] = xv;
            sh_yt[(t + 1) & 1] = y[(size_t)b * kT + t + 1];
        }
        __syncthreads();                                   // (B)
    }

    // Epilogue: tail for t = kT-1 (all waves run it; w0 stores)
    tail_step(kT - 1);
}

extern "C" void kernel_launch(void* const* d_in, const int* in_sizes, int n_in,
                              void* d_out, int out_size, void* d_ws, size_t ws_size,
                              hipStream_t stream)
{
    const float* x   = (const float*)d_in[0];
    const float* y   = (const float*)d_in[1];
    const float* U   = (const float*)d_in[2];
    const float* S   = (const float*)d_in[3];
    const float* A   = (const float*)d_in[4];
    const float* Wih = (const float*)d_in[5];
    const float* Whh = (const float*)d_in[6];
    const float* bih = (const float*)d_in[7];
    const float* bhh = (const float*)d_in[8];
    const float* Wd  = (const float*)d_in[9];
    const float* bd  = (const float*)d_in[10];

    float* WhhT  = (float*)d_ws;                 // 49152 floats = 192 KB scratch
    float* out_o = (float*)d_out;                // (B, T) preds
    float* out_p = out_o + kB * kT;              // (B, T, 1) penalties

    hipLaunchKernelGGL(whh_transpose, dim3(192), dim3(256), 0, stream, Whh, WhhT);
    hipLaunchKernelGGL(disc_kernel, dim3(kB), dim3(512), 0, stream,
                       x, y, U, S, A, Wih, bih, bhh, Wd, bd, WhhT, out_o, out_p);
}

// Round 7
// 2644.601 us; speedup vs baseline: 1.0882x; 1.0882x over previous
//
#include <hip/hip_runtime.h>
#include <math.h>

constexpr int kB  = 256;
constexpr int kT  = 512;
constexpr int kNS = 64;
constexpr int kH  = 128;

// WhhT rows 0..255 cached in LDS (fp32), padded to 132 floats/row: lane bank
// = 4*(u+k4) % 32 -> all 32 banks hit uniformly per b128 read.
constexpr int kWRowsLds = 256;
constexpr int kWPad     = 132;

__device__ __forceinline__ float sigmoidf_(float v) { return 1.0f / (1.0f + __expf(-v)); }
// fast tanh via exp (saturates correctly at +/-1; verified absmax-neutral in R15)
__device__ __forceinline__ float tanhf_(float v) {
    return 1.0f - 2.0f / (1.0f + __expf(2.0f * v));
}
__device__ __forceinline__ float dot4(float4 a, float4 b) {
    return a.x*b.x + a.y*b.y + a.z*b.z + a.w*b.w;
}

// ---- DPP cross-lane reduce (4 VALU DPP + 2 DS ops) ------------------------
template <int CTRL>
__device__ __forceinline__ float dppf(float x) {
    return __int_as_float(__builtin_amdgcn_mov_dpp(__float_as_int(x), CTRL, 0xf, 0xf, true));
}
__device__ __forceinline__ float red_max64(float x) {
    x = fmaxf(x, dppf<0xB1>(x));
    x = fmaxf(x, dppf<0x4E>(x));
    x = fmaxf(x, dppf<0x124>(x));
    x = fmaxf(x, dppf<0x128>(x));
    x = fmaxf(x, __shfl_xor(x, 16, 64));
    x = fmaxf(x, __shfl_xor(x, 32, 64));
    return x;
}
__device__ __forceinline__ float red_sum64(float x) {
    x += dppf<0xB1>(x);
    x += dppf<0x4E>(x);
    x += dppf<0x124>(x);
    x += dppf<0x128>(x);
    x += __shfl_xor(x, 16, 64);
    x += __shfl_xor(x, 32, 64);
    return x;
}

// One-time: transpose Whh[128][384] -> WhhT[384][128] in d_ws.
extern "C" __global__ void __launch_bounds__(256)
whh_transpose(const float* __restrict__ Whh, float* __restrict__ WhhT) {
    const int o = blockIdx.x * 256 + threadIdx.x;   // 0..49151
    const int j = o >> 7, k = o & 127;
    WhhT[o] = Whh[k * 384 + j];
}

// One block (512 threads) per batch row. 3 barriers/step (R4 structure —
// verified best attractor; R15's 2-barrier fusion serialized tail+gh and
// regressed).
//   PA: gh hi-chunks (+=, waves 1-6) | K rows + DPP max-reduce (all waves)
//   PB: einsum (all waves) + distributed GRU (threads 0-127, fast tanh)
//   PE: w0 tail (DPP sums) | w1-4 gh chunks 0..15 (LDS) | w5-6 chunks 0..23
//       (L2) | w7 x/y prefetch
extern "C" __global__ void __launch_bounds__(512, 2)
disc_kernel(const float* __restrict__ x,   const float* __restrict__ y,
            const float* __restrict__ U,   const float* __restrict__ S,
            const float* __restrict__ A,   const float* __restrict__ Wih,
            const float* __restrict__ bih, const float* __restrict__ bhh,
            const float* __restrict__ Wd,  const float* __restrict__ bd,
            const float* __restrict__ WhhT,
            float* __restrict__ out_o,  float* __restrict__ out_p)
{
    const int b    = blockIdx.x;
    const int tid  = threadIdx.x;
    const int lane = tid & 63;
    const int wid  = tid >> 6;
    const int hb   = tid & 1;

    __shared__ __align__(16) float sh_K[768];
    __shared__ __align__(16) float sh_part[512];
    __shared__ __align__(16) float sh_part2[512];
    __shared__ __align__(16) float sh_gh[384];
    __shared__ __align__(16) float sh_h[2][kH];      // parity double buffer
    __shared__ __align__(16) float sh_s[kNS];
    __shared__ __align__(16) float sh_Wih[4 * 384];
    __shared__ __align__(16) float sh_bih[384];
    __shared__ __align__(16) float sh_bhh[384];
    __shared__ float sh_Wd[384];
    __shared__ float sh_bd[4];
    __shared__ float sh_encA[8];                     // per-wave max of kk_a
    __shared__ float sh_encB[8];                     // per-wave max of kk_b
    __shared__ __align__(16) float sh_xt[4];
    __shared__ float sh_x2, sh_s2, sh_err;
    __shared__ float sh_yt[2];
    // 256 x 132 fp32 = 135168 B; block total ~152.5 KB (<=160 KB, 1 blk/CU)
    __shared__ __align__(16) float sh_W[kWRowsLds * kWPad];

    // ---- Persistent register caches (R6 layout; AT THE REGISTER WALL — do
    // not add more persistent per-thread state, it spills to scratch) -------
    const float4* S4 = reinterpret_cast<const float4*>(S);
    const float4* U4 = reinterpret_cast<const float4*>(U);

    float4 Sa[16]; float4 Ua; float Ca;       // full K-row = tid
    float4 Sb[8];  float Ub0, Ub1; float Cb;  // half of K-row 512+(tid>>1)
    {
        float ss = 0.f;
#pragma unroll
        for (int j = 0; j < 16; ++j) { Sa[j] = S4[tid * 16 + j]; ss += dot4(Sa[j], Sa[j]); }
        Ua = U4[tid];
        Ca = -0.5f * (dot4(Ua, Ua) + ss);
    }
    const int pbrow = 512 + (tid >> 1);
    {
        float ss = 0.f;
#pragma unroll
        for (int j = 0; j < 8; ++j) { Sb[j] = S4[pbrow * 16 + hb * 8 + j]; ss += dot4(Sb[j], Sb[j]); }
        Ub0 = U[pbrow * 4 + hb * 2 + 0];
        Ub1 = U[pbrow * 4 + hb * 2 + 1];
        Cb = -0.5f * (Ub0*Ub0 + Ub1*Ub1 + ss);
    }
    // Einsum A caches — wave-uniform chunk mapping (conflict-free K broadcast)
    float A1[64];                              // (m=wid>>2, cc=wid&3), n=lane
#pragma unroll
    for (int dd = 0; dd < 64; ++dd)
        A1[dd] = A[((wid >> 2) * 256 + (wid & 3) * 64 + dd) * 64 + lane];
    float A2[32];                              // m=2, cc2=wid>>1, half=wid&1, n=lane
#pragma unroll
    for (int dd = 0; dd < 32; ++dd)
        A2[dd] = A[(512 + (wid >> 1) * 64 + (wid & 1) * 32 + dd) * 64 + lane];

    // PE-wave0 persistent gate state
    float g0 = 0.3333f, g1 = 0.3333f, g2 = 0.3334f;

    // ---- LDS preload -----------------------------------------------------
    for (int i = tid; i < 1536; i += 512) sh_Wih[i] = Wih[i];
    for (int i = tid; i < 384; i += 512) {
        sh_bih[i] = bih[i];
        sh_bhh[i] = bhh[i];
        sh_gh[i]  = bhh[i];                   // gh(t=0) with h=0
        sh_Wd[i]  = (i < 381) ? Wd[i] : 0.f;  // zero-pad cols 381..383
    }
    // One-time WhhT rows 0..255 -> padded LDS (float4 copy, 16 iters/thr)
    for (int i4 = tid; i4 < kWRowsLds * 32; i4 += 512) {
        const int r = i4 >> 5, c4 = i4 & 31;
        reinterpret_cast<float4*>(sh_W + r * kWPad)[c4] =
            reinterpret_cast<const float4*>(WhhT)[i4];
    }
    if (tid < 3) sh_bd[tid] = bd[tid];
    if (tid < kNS) sh_s[tid] = 0.f;
    if (tid < kH)  { sh_h[0][tid] = 0.f; sh_h[1][tid] = 0.f; }
    if (tid == 0) {
        sh_err = 1.0f; sh_s2 = 0.f;
        float4 xv = reinterpret_cast<const float4*>(x)[(size_t)b * kT];
        reinterpret_cast<float4*>(sh_xt)[0] = xv;
        sh_x2 = dot4(xv, xv);
        sh_yt[0] = y[(size_t)b * kT];
    }
    __syncthreads();

    for (int t = 0; t < kT; ++t) {
        const int par  = t & 1;
        const int par1 = (t + 1) & 1;

        // ===== PA: gh hi-chunks (waves 1-6) + K rows (all waves) ===========
        // gh-add uses h_t = sh_h[par] (written PB(t-1); t=0: zeros -> +0).
        // Same thread owns row u in PE and PA -> no race; barrier(3) orders.
        if (wid >= 1 && wid <= 4) {
            const int u = tid - 64;                        // 0..255 (LDS rows)
            const float4* W4 = reinterpret_cast<const float4*>(sh_W + u * kWPad);
            const float4* h4 = reinterpret_cast<const float4*>(sh_h[par]);
            float ga = 0.f, gb = 0.f;                      // 2 chains for ILP
#pragma unroll
            for (int k4 = 16; k4 < 32; k4 += 2) {
                ga += dot4(h4[k4],     W4[k4]);
                gb += dot4(h4[k4 + 1], W4[k4 + 1]);
            }
            sh_gh[u] += ga + gb;
        } else if (wid == 5 || wid == 6) {
            const int u = 256 + (tid - 320);               // 256..383 (L2 rows)
            const float4* W4 = reinterpret_cast<const float4*>(WhhT) + u * 32;
            const float4* h4 = reinterpret_cast<const float4*>(sh_h[par]);
            float ga = 0.f, gb = 0.f;
#pragma unroll
            for (int k4 = 24; k4 < 32; k4 += 2) {
                ga += dot4(h4[k4],     W4[k4]);
                gb += dot4(h4[k4 + 1], W4[k4 + 1]);
            }
            sh_gh[u] += ga + gb;
        }
        // K rows: s read ONCE (16 b128 broadcast); both db halves, hb-selected.
        {
            const float scal = -0.5f * (sh_x2 + sh_s2);
            const float4 xt4 = reinterpret_cast<const float4*>(sh_xt)[0];
            const float4* s4 = reinterpret_cast<const float4*>(sh_s);
            float da0 = 0.f, da1 = 0.f, dblo = 0.f, dbhi = 0.f;
#pragma unroll
            for (int j = 0; j < 8; ++j) {
                const float4 sv0 = s4[j];              // s[0..31]
                const float4 sv1 = s4[8 + j];          // s[32..63]
                da0  += dot4(sv0, Sa[j]);
                da1  += dot4(sv1, Sa[8 + j]);
                dblo += dot4(sv0, Sb[j]);              // pairing if hb==0
                dbhi += dot4(sv1, Sb[j]);              // pairing if hb==1
            }
            const float db = hb ? dbhi : dblo;
            const float kk_a = __expf(scal + Ca + dot4(xt4, Ua) + da0 + da1);
            const float xbp  = hb ? (xt4.z*Ub0 + xt4.w*Ub1) : (xt4.x*Ub0 + xt4.y*Ub1);
            const float ph   = db + Cb + xbp;
            const float po   = dppf<0xB1>(ph);             // xor1 via quad_perm
            const float kk_b = __expf(scal + ph + po);
            sh_K[tid] = kk_a;
            if (hb == 0) sh_K[512 + (tid >> 1)] = kk_b;
            const float mA = red_max64(kk_a);
            const float mB = red_max64(kk_b);
            if (lane == 0) { sh_encA[wid] = mA; sh_encB[wid] = mB; }
        }
        __syncthreads();                                  // (1)

        // ===== PB: einsum (all waves) + distributed GRU (threads 0-127) ====
        {
            const float4* K4 = reinterpret_cast<const float4*>(sh_K + wid * 64);
            float acc = 0.f;
#pragma unroll
            for (int j = 0; j < 16; ++j) {                // wave-uniform broadcast
                const float4 kv = K4[j];
                acc += kv.x*A1[4*j] + kv.y*A1[4*j+1] + kv.z*A1[4*j+2] + kv.w*A1[4*j+3];
            }
            sh_part[tid] = acc;
            const float4* K4b = reinterpret_cast<const float4*>(
                                    sh_K + 512 + (wid >> 1) * 64 + (wid & 1) * 32);
            float accb = 0.f;
#pragma unroll
            for (int j = 0; j < 8; ++j) {                 // wave-uniform broadcast
                const float4 kv = K4b[j];
                accb += kv.x*A2[4*j] + kv.y*A2[4*j+1] + kv.z*A2[4*j+2] + kv.w*A2[4*j+3];
            }
            sh_part2[tid] = accb;
        }
        if (tid < 128) {
            const float e0 = fmaxf(fmaxf(sh_encA[0], sh_encA[1]), fmaxf(sh_encA[2], sh_encA[3]));
            const float e1 = fmaxf(fmaxf(sh_encA[4], sh_encA[5]), fmaxf(sh_encA[6], sh_encA[7]));
            const float e2 = fmaxf(fmaxf(fmaxf(sh_encB[0], sh_encB[1]), fmaxf(sh_encB[2], sh_encB[3])),
                                   fmaxf(fmaxf(sh_encB[4], sh_encB[5]), fmaxf(sh_encB[6], sh_encB[7])));
            const float er = sh_err;
            const int j = tid;
            const float gir = sh_bih[j]       + e0*sh_Wih[j]        + e1*sh_Wih[384 + j]
                                              + e2*sh_Wih[768 + j]  + er*sh_Wih[1152 + j];
            const float giz = sh_bih[128 + j] + e0*sh_Wih[128 + j]  + e1*sh_Wih[512 + j]
                                              + e2*sh_Wih[896 + j]  + er*sh_Wih[1280 + j];
            const float gin = sh_bih[256 + j] + e0*sh_Wih[256 + j]  + e1*sh_Wih[640 + j]
                                              + e2*sh_Wih[1024 + j] + er*sh_Wih[1408 + j];
            const float r  = sigmoidf_(gir + sh_gh[j]);
            const float z  = sigmoidf_(giz + sh_gh[128 + j]);
            const float nn = tanhf_(gin + r * sh_gh[256 + j]);
            sh_h[par1][j] = (1.f - z) * nn + z * sh_h[par][j];
        }
        __syncthreads();                                  // (2)

        // ===== PE: w0 tail | w1-4 gh lo (LDS) | w5-6 gh lo (L2) | w7 pref ==
        if (wid == 0) {
            const float hA = sh_h[par1][lane];
            const float hB = sh_h[par1][64 + lane];
            const float theta = sigmoidf_(sh_h[par1][127]);
            float l0 = hA * sh_Wd[lane*3+0] + hB * sh_Wd[(64+lane)*3+0];
            float l1 = hA * sh_Wd[lane*3+1] + hB * sh_Wd[(64+lane)*3+1];
            float l2 = hA * sh_Wd[lane*3+2] + hB * sh_Wd[(64+lane)*3+2];
            l0 = red_sum64(l0);
            l1 = red_sum64(l1);
            l2 = red_sum64(l2);
            l0 += sh_bd[0]; l1 += sh_bd[1]; l2 += sh_bd[2];
            const float mx = fmaxf(l0, fmaxf(l1, l2));
            const float x0 = __expf(l0 - mx), x1 = __expf(l1 - mx), x2 = __expf(l2 - mx);
            const float inv = theta / (x0 + x1 + x2);
            const float omt = 1.f - theta;
            g0 = x0*inv + g0*omt;
            g1 = x1*inv + g1*omt;
            g2 = x2*inv + g2*omt;
            const float ns0 = (sh_part[lane]       + sh_part[64 + lane])
                            + (sh_part[128 + lane] + sh_part[192 + lane]);
            const float ns1 = (sh_part[256 + lane] + sh_part[320 + lane])
                            + (sh_part[384 + lane] + sh_part[448 + lane]);
            const float ns2 = ((sh_part2[lane]       + sh_part2[64 + lane])
                            +  (sh_part2[128 + lane] + sh_part2[192 + lane]))
                            + ((sh_part2[256 + lane] + sh_part2[320 + lane])
                            +  (sh_part2[384 + lane] + sh_part2[448 + lane]));
            const float sn = g0*ns0 + g1*ns1 + g2*ns2;
            sh_s[lane] = sn;
            if (lane == 0)
                out_p[(size_t)b * kT + t] = g0*(1.f-g0) + g1*(1.f-g1) + g2*(1.f-g2);
            if (lane == 63) {
                out_o[(size_t)b * kT + t] = sn;
                sh_err = sn - sh_yt[par];
            }
            const float ss = red_sum64(sn * sn);
            if (lane == 0) sh_s2 = ss;
        } else if (wid <= 4) {                             // waves 1-4: rows 0..255 (LDS)
            const int u = tid - 64;                        // 0..255
            const float4* W4 = reinterpret_cast<const float4*>(sh_W + u * kWPad);
            const float4* h4 = reinterpret_cast<const float4*>(sh_h[par1]);
            float ga = sh_bhh[u], gb = 0.f;                // 2 chains for ILP
#pragma unroll
            for (int k4 = 0; k4 < 16; k4 += 2) {
                ga += dot4(h4[k4],     W4[k4]);
                gb += dot4(h4[k4 + 1], W4[k4 + 1]);
            }
            sh_gh[u] = ga + gb;                            // hi-chunks added in PA(t+1)
        } else if (wid <= 6) {                             // waves 5-6: rows 256..383 (L2)
            const int u = 256 + (tid - 320);               // 256..383
            const float4* W4 = reinterpret_cast<const float4*>(WhhT) + u * 32;
            const float4* h4 = reinterpret_cast<const float4*>(sh_h[par1]);
            float ga = sh_bhh[u], gb = 0.f;
#pragma unroll
            for (int k4 = 0; k4 < 24; k4 += 2) {
                ga += dot4(h4[k4],     W4[k4]);
                gb += dot4(h4[k4 + 1], W4[k4 + 1]);
            }
            sh_gh[u] = ga + gb;                            // chunks 24..31 in PA(t+1)
        } else {                                           // wave 7: x/y prefetch
            if (lane == 0 && (t + 1) < kT) {
                float4 xv = reinterpret_cast<const float4*>(x)[(size_t)b * kT + t + 1];
                reinterpret_cast<float4*>(sh_xt)[0] = xv;
                sh_x2 = dot4(xv, xv);
                sh_yt[par1] = y[(size_t)b * kT + t + 1];
            }
        }
        __syncthreads();                                  // (3)
    }
}

extern "C" void kernel_launch(void* const* d_in, const int* in_sizes, int n_in,
                              void* d_out, int out_size, void* d_ws, size_t ws_size,
                              hipStream_t stream)
{
    const float* x   = (const float*)d_in[0];
    const float* y   = (const float*)d_in[1];
    const float* U   = (const float*)d_in[2];
    const float* S   = (const float*)d_in[3];
    const float* A   = (const float*)d_in[4];
    const float* Wih = (const float*)d_in[5];
    const float* Whh = (const float*)d_in[6];
    const float* bih = (const float*)d_in[7];
    const float* bhh = (const float*)d_in[8];
    const float* Wd  = (const float*)d_in[9];
    const float* bd  = (const float*)d_in[10];

    float* WhhT  = (float*)d_ws;                 // 49152 floats = 192 KB scratch
    float* out_o = (float*)d_out;                // (B, T) preds
    float* out_p = out_o + kB * kT;              // (B, T, 1) penalties

    hipLaunchKernelGGL(whh_transpose, dim3(192), dim3(256), 0, stream, Whh, WhhT);
    hipLaunchKernelGGL(disc_kernel, dim3(kB), dim3(512), 0, stream,
                       x, y, U, S, A, Wih, bih, bhh, Wd, bd, WhhT, out_o, out_p);
}